// Round 7
// baseline (584.106 us; speedup 1.0000x reference)
//
#include <hip/hip_runtime.h>

#define GS 128
#define GS3 (GS*GS*GS)
#define NPTS 150000
#define NBATCH 2
#define BN_TOT (NBATCH*NPTS)       // 300000
#define CONV_BLOCKS 1172           // 256 rows/block
#define BN_PAD (CONV_BLOCKS*256)   // 300032
#define ZROW   BN_PAD              // zero feature row index
#define EPS 1e-5f
#define NBKT 8192                  // 2 batches * 16^3 coarse buckets
#define EB   6912                  // entry slots per block (27*256 worst case)

// ws layout (~94 MB)
#define OFF_GRID   0ull
#define SZ_GRID    ((size_t)NBATCH*GS3*4)            // 16,777,216
#define OFF_WFRAG  (OFF_GRID + SZ_GRID)
#define SZ_WFRAG   ((size_t)27*4096*2)               // 221,184
#define OFF_STATS  (OFF_WFRAG + SZ_WFRAG)            // 512
#define OFF_CNT    (OFF_STATS + 512)                 // 32,768
#define OFF_CUR    (OFF_CNT + NBKT*4)                // 32,768
#define OFF_SIDX   (OFF_CUR + NBKT*4)                // 1,200,128
#define OFF_CSORT  (OFF_SIDX + 1200128)              // BN_PAD*16
#define OFF_FB16S  (OFF_CSORT + (size_t)BN_PAD*16)   // (BN_PAD+1)*128
#define OFF_ENT    (OFF_FB16S + (size_t)(BN_PAD+1)*128)  // 1172*6912*4 = 32.4MB
#define OFF_CNTS   (OFF_ENT + (size_t)CONV_BLOCKS*EB*4)  // 1172*32*4

typedef __attribute__((ext_vector_type(8))) short bf16x8;
typedef __attribute__((ext_vector_type(4))) float f32x4;
typedef unsigned int u32;

__device__ __forceinline__ short f2bf(float f) {
    union { float f; unsigned u; } v; v.f = f;
    unsigned rr = v.u + 0x7fffu + ((v.u >> 16) & 1u);   // RNE
    return (short)(rr >> 16);
}

// ---------- kernel 1: grid scatter (max orig pid) + bucket histogram ----------
__global__ __launch_bounds__(256) void k_count(const int* __restrict__ coords,
                                               int* __restrict__ grid,
                                               u32* __restrict__ cnt) {
    int p = blockIdx.x*256 + threadIdx.x;
    if (p >= BN_TOT) return;
    int x = coords[p*3+0], y = coords[p*3+1], z = coords[p*3+2];
    int b = (p >= NPTS);
    atomicMax(&grid[(b<<21) | (x<<14) | (y<<7) | z], p);
    atomicAdd(&cnt[(b<<12) | ((x>>3)<<8) | ((y>>3)<<4) | (z>>3)], 1u);
}

// ---------- kernel 2: exclusive scan of 8192 bucket counts ----------
__global__ __launch_bounds__(1024) void k_scan(const u32* __restrict__ cnt,
                                               u32* __restrict__ cur) {
    __shared__ u32 ps[1024];
    int t = threadIdx.x;
    u32 l[8]; u32 s = 0;
    #pragma unroll
    for (int i = 0; i < 8; ++i) { l[i] = cnt[t*8+i]; s += l[i]; }
    ps[t] = s; __syncthreads();
    for (int off = 1; off < 1024; off <<= 1) {
        u32 v = (t >= off) ? ps[t-off] : 0u; __syncthreads();
        ps[t] += v; __syncthreads();
    }
    u32 run = (t == 0) ? 0u : ps[t-1];
    #pragma unroll
    for (int i = 0; i < 8; ++i) { cur[t*8+i] = run; run += l[i]; }
}

// ---------- kernel 3: place points in bucket order + bf16 features ----------
__global__ __launch_bounds__(256) void k_place(const float* __restrict__ feats,
                                               const int* __restrict__ coords,
                                               u32* __restrict__ cur,
                                               int* __restrict__ sortidx,
                                               int4* __restrict__ csorted,
                                               ushort* __restrict__ fb16s) {
    int p = blockIdx.x*256 + threadIdx.x;
    if (p >= BN_PAD) return;
    if (p >= BN_TOT) { csorted[p] = make_int4(-9,-9,-9,0); return; }
    int x = coords[p*3+0], y = coords[p*3+1], z = coords[p*3+2];
    int b = (p >= NPTS);
    int bkt = (b<<12) | ((x>>3)<<8) | ((y>>3)<<4) | (z>>3);
    int pos = (int)atomicAdd(&cur[bkt], 1u);
    sortidx[p] = pos;
    csorted[pos] = make_int4(x, y, z, p);
    const float4* s = (const float4*)(feats + (size_t)p*64);
    ushort* d = fb16s + (size_t)pos*64;
    #pragma unroll
    for (int i = 0; i < 8; ++i) {
        float4 a = s[2*i], c = s[2*i+1];
        ushort4 u0 = { (ushort)f2bf(a.x),(ushort)f2bf(a.y),(ushort)f2bf(a.z),(ushort)f2bf(a.w) };
        ushort4 u1 = { (ushort)f2bf(c.x),(ushort)f2bf(c.y),(ushort)f2bf(c.z),(ushort)f2bf(c.w) };
        ((ushort4*)d)[2*i] = u0; ((ushort4*)d)[2*i+1] = u1;
    }
}

// ---------- kernel 4: compacted rulebook per conv block ----------
// For block blk, per k: list of packed (sid<<8 | row_local) for valid pairs,
// lists concatenated in k order at entries[blk*EB]; counts at cnts[blk*32+k].
__global__ __launch_bounds__(256) void k_rules(const int4* __restrict__ csorted,
                                               const int* __restrict__ grid,
                                               const int* __restrict__ sortidx,
                                               int* __restrict__ entries,
                                               int* __restrict__ cnts) {
    __shared__ u32 wcnt[4];
    __shared__ u32 basev;
    const int tid = threadIdx.x, lane = tid & 63, wv = tid >> 6;
    const int blk = blockIdx.x;
    const int row = tid;
    const int s = blk*256 + row;
    int4 c = csorted[s];
    const bool pad = (s >= BN_TOT);
    const int gb = (c.w >= NPTS) ? GS3 : 0;

    // all 27 probes up front (full ILP, no syncs between loads)
    int sid[27];
    #pragma unroll
    for (int k = 0; k < 27; ++k) {
        int dx = k/9 - 1, dy = (k/3)%3 - 1, dz = k%3 - 1;   // compile-time
        int nx = c.x+dx, ny = c.y+dy, nz = c.z+dz;
        int ok = (int)(!pad & ((unsigned)nx < 128u) & ((unsigned)ny < 128u) &
                       ((unsigned)nz < 128u));
        int pid = grid[gb + ((nx&127)<<14) + ((ny&127)<<7) + (nz&127)];
        pid = ok ? pid : -1;
        int sv = sortidx[pid < 0 ? 0 : pid];
        sid[k] = (pid >= 0) ? sv : ZROW;
    }

    if (tid == 0) basev = 0;
    int* eb = entries + (size_t)blk * EB;
    __syncthreads();
    #pragma unroll 1
    for (int k = 0; k < 27; ++k) {
        bool pred = (sid[k] != ZROW);
        unsigned long long b = __ballot(pred);
        if (lane == 0) wcnt[wv] = (u32)__popcll(b);
        __syncthreads();
        u32 off = basev;
        u32 w0 = wcnt[0], w1 = wcnt[1], w2 = wcnt[2], w3 = wcnt[3];
        u32 woff = (wv > 0 ? w0 : 0u) + (wv > 1 ? w1 : 0u) + (wv > 2 ? w2 : 0u);
        u32 tot = w0 + w1 + w2 + w3;
        u32 lc = (u32)__popcll(b & ((1ull << lane) - 1ull));
        if (pred) eb[off + woff + lc] = (sid[k] << 8) | row;
        __syncthreads();
        if (tid == 0) { basev = off + tot; cnts[blk*32 + k] = (int)tot; }
    }
}

// ---------- kernel 5: weight -> bf16 MFMA B-fragments ----------
__global__ __launch_bounds__(256) void k_prefrag(const float* __restrict__ w,
                                                 short* __restrict__ wfrag) {
    int t = blockIdx.x * 256 + threadIdx.x;
    if (t >= 27*4096) return;
    int i    = t & 7;
    int lane = (t >> 3) & 63;
    int tt   = (t >> 9) & 3;
    int c    = (t >> 11) & 1;
    int k    = t >> 12;
    int kk = c*32 + (lane >> 4)*8 + i;
    int co = tt*16 + (lane & 15);
    wfrag[t] = f2bf(w[(k*64 + kk)*64 + co]);
}

// ---------- kernel 6: sparse rulebook conv, LDS scatter-add ----------
// Block = 256 output rows, f32 out-accumulator in LDS (stride 68).
// Waves free-run over flat tile list (16 valid pairs of one k per tile):
// gather A rows -> 8 MFMA (B from L2-hot wfrag) -> ds_add_f32 scatter.
// No barriers in main loop; cross-k collisions handled by LDS atomics.
__global__ __launch_bounds__(256, 2) void k_conv(
    const ushort* __restrict__ fb16s,
    const int4* __restrict__ csorted,
    const int* __restrict__ entries,
    const int* __restrict__ cnts,
    const ushort* __restrict__ wfrag,
    float* __restrict__ out,
    float* __restrict__ gstats)
{
    __shared__ float oacc[256*68];      // 69,632 B, stride 68 (16B-aligned rows)
    __shared__ int   cl[27];
    __shared__ float bsum[64], bsq[64];

    const int tid  = threadIdx.x;
    const int lane = tid & 63;
    const int wv   = tid >> 6;
    const int r    = lane & 15;
    const int seg  = lane >> 4;
    const int blk  = blockIdx.x;
    const int p0b  = blk * 256;

    #pragma unroll
    for (int i = 0; i < 68; ++i) oacc[i*256 + tid] = 0.f;
    if (tid < 27) cl[tid] = cnts[blk*32 + tid];
    if (tid < 64) { bsum[tid] = 0.f; bsq[tid] = 0.f; }
    __syncthreads();

    const int* eb = entries + (size_t)blk * EB;
    const bf16x8* wfp = (const bf16x8*)wfrag;

    int ebase = 0, tbase = 0;
    #pragma unroll 1
    for (int k = 0; k < 27; ++k) {
        const int cnt = cl[k];
        const int nt = (cnt + 15) >> 4;
        const bf16x8* wb = wfp + (size_t)k*512;
        int t = (wv - tbase) & 3;                  // flat tiles striped over waves
        for (; t < nt; t += 4) {
            int ei = t*16 + r;
            int pe = eb[ebase + (ei < cnt ? ei : cnt-1)];
            if (ei >= cnt) pe = (ZROW << 8);       // dummy: zero A row, row_local 0
            int sid = pe >> 8;
            const ushort* ap = fb16s + (size_t)sid*64 + seg*8;
            bf16x8 a0 = *(const bf16x8*)(ap);
            bf16x8 a1 = *(const bf16x8*)(ap + 32);
            bf16x8 b0 = wb[0*64+lane], b1 = wb[1*64+lane],
                   b2 = wb[2*64+lane], b3 = wb[3*64+lane],
                   b4 = wb[4*64+lane], b5 = wb[5*64+lane],
                   b6 = wb[6*64+lane], b7 = wb[7*64+lane];
            f32x4 q0 = {0,0,0,0}, q1 = {0,0,0,0}, q2 = {0,0,0,0}, q3 = {0,0,0,0};
            q0 = __builtin_amdgcn_mfma_f32_16x16x32_bf16(a0, b0, q0, 0,0,0);
            q1 = __builtin_amdgcn_mfma_f32_16x16x32_bf16(a0, b1, q1, 0,0,0);
            q2 = __builtin_amdgcn_mfma_f32_16x16x32_bf16(a0, b2, q2, 0,0,0);
            q3 = __builtin_amdgcn_mfma_f32_16x16x32_bf16(a0, b3, q3, 0,0,0);
            q0 = __builtin_amdgcn_mfma_f32_16x16x32_bf16(a1, b4, q0, 0,0,0);
            q1 = __builtin_amdgcn_mfma_f32_16x16x32_bf16(a1, b5, q1, 0,0,0);
            q2 = __builtin_amdgcn_mfma_f32_16x16x32_bf16(a1, b6, q2, 0,0,0);
            q3 = __builtin_amdgcn_mfma_f32_16x16x32_bf16(a1, b7, q3, 0,0,0);
            // scatter-add: C/D col=r (+16q), entry row = seg*4+j
            #pragma unroll
            for (int j = 0; j < 4; ++j) {
                int rw = __shfl(pe, seg*4 + j, 64) & 0xFF;
                float* dst = &oacc[rw*68 + r];
                atomicAdd(dst +  0, q0[j]);
                atomicAdd(dst + 16, q1[j]);
                atomicAdd(dst + 32, q2[j]);
                atomicAdd(dst + 48, q3[j]);
            }
        }
        ebase += cnt; tbase += nt;
    }
    __syncthreads();

    // ---- epilogue: out_acc -> out[orig pid], fused stats ----
    const int rg = tid >> 2, c4 = tid & 3;
    float s[16], sq[16];
    #pragma unroll
    for (int i = 0; i < 16; ++i) { s[i] = 0.f; sq[i] = 0.f; }
    #pragma unroll
    for (int p = 0; p < 4; ++p) {
        int row = p*64 + rg;
        const float* src = &oacc[row*68 + c4*16];
        float4 v0 = *(const float4*)(src +  0);
        float4 v1 = *(const float4*)(src +  4);
        float4 v2 = *(const float4*)(src +  8);
        float4 v3 = *(const float4*)(src + 12);
        const float vv[16] = { v0.x,v0.y,v0.z,v0.w, v1.x,v1.y,v1.z,v1.w,
                               v2.x,v2.y,v2.z,v2.w, v3.x,v3.y,v3.z,v3.w };
        #pragma unroll
        for (int i = 0; i < 16; ++i) { s[i] += vv[i]; sq[i] += vv[i]*vv[i]; }
        int srow = p0b + row;
        if (srow < BN_TOT) {
            int opid = csorted[srow].w;
            float4* ob = (float4*)(out + (size_t)opid*64 + c4*16);
            ob[0] = v0; ob[1] = v1; ob[2] = v2; ob[3] = v3;
        }
    }
    #pragma unroll
    for (int i = 0; i < 16; ++i) {
        atomicAdd(&bsum[c4*16 + i], s[i]);
        atomicAdd(&bsq [c4*16 + i], sq[i]);
    }
    __syncthreads();
    if (tid < 64) { atomicAdd(&gstats[tid], bsum[tid]); atomicAdd(&gstats[64+tid], bsq[tid]); }
}

// ---------- kernel 7: normalize + affine + ReLU, in place ----------
__global__ __launch_bounds__(256) void k_norm(float* __restrict__ out,
                                              const float* __restrict__ stats,
                                              const float* __restrict__ gamma,
                                              const float* __restrict__ beta) {
    int i = blockIdx.x*256 + threadIdx.x;
    const int n4 = BN_TOT*16;
    if (i >= n4) return;
    float4 v = ((const float4*)out)[i];
    int ch = (i & 15) * 4;
    float o[4] = {v.x, v.y, v.z, v.w};
    float rp[4];
    #pragma unroll
    for (int j = 0; j < 4; ++j) {
        int c = ch + j;
        float mean = stats[c] * (1.f/BN_TOT);
        float var  = stats[64+c] * (1.f/BN_TOT) - mean*mean;
        float y = (o[j] - mean) * rsqrtf(var + EPS) * gamma[c] + beta[c];
        rp[j] = fmaxf(y, 0.f);
    }
    float4 rv; rv.x = rp[0]; rv.y = rp[1]; rv.z = rp[2]; rv.w = rp[3];
    ((float4*)out)[i] = rv;
}

extern "C" void kernel_launch(void* const* d_in, const int* in_sizes, int n_in,
                              void* d_out, int out_size, void* d_ws, size_t ws_size,
                              hipStream_t stream) {
    const float* feats  = (const float*)d_in[0];
    const int*   coords = (const int*)d_in[1];
    const float* weight = (const float*)d_in[2];
    const float* gamma  = (const float*)d_in[3];
    const float* beta   = (const float*)d_in[4];
    float* out = (float*)d_out;

    char*   ws      = (char*)d_ws;
    int*    grid    = (int*)(ws + OFF_GRID);
    short*  wfrag   = (short*)(ws + OFF_WFRAG);
    float*  stats   = (float*)(ws + OFF_STATS);
    u32*    cnt     = (u32*)(ws + OFF_CNT);
    u32*    cur     = (u32*)(ws + OFF_CUR);
    int*    sortidx = (int*)(ws + OFF_SIDX);
    int4*   csorted = (int4*)(ws + OFF_CSORT);
    ushort* fb16s   = (ushort*)(ws + OFF_FB16S);
    int*    entries = (int*)(ws + OFF_ENT);
    int*    cnts    = (int*)(ws + OFF_CNTS);

    hipMemsetAsync(grid,  0xFF, SZ_GRID, stream);
    hipMemsetAsync(stats, 0, 512, stream);
    hipMemsetAsync(cnt,   0, NBKT*4, stream);
    hipMemsetAsync(fb16s + (size_t)BN_TOT*64, 0,
                   (size_t)(BN_PAD + 1 - BN_TOT)*128, stream);   // pads + ZROW

    k_count  <<<(BN_TOT + 255)/256, 256, 0, stream>>>(coords, grid, cnt);
    k_scan   <<<1, 1024, 0, stream>>>(cnt, cur);
    k_place  <<<(BN_PAD + 255)/256, 256, 0, stream>>>(feats, coords, cur,
                                                      sortidx, csorted, fb16s);
    k_rules  <<<CONV_BLOCKS, 256, 0, stream>>>(csorted, grid, sortidx,
                                               entries, cnts);
    k_prefrag<<<(27*4096)/256, 256, 0, stream>>>(weight, wfrag);
    k_conv   <<<CONV_BLOCKS, 256, 0, stream>>>(fb16s, csorted, entries, cnts,
                                               (const ushort*)wfrag, out, stats);
    k_norm   <<<(BN_TOT*16)/256, 256, 0, stream>>>(out, stats, gamma, beta);
}

// Round 8
// 226.990 us; speedup vs baseline: 2.5733x; 2.5733x over previous
//
#include <hip/hip_runtime.h>

#define GS 128
#define GS3 (GS*GS*GS)
#define NPTS 150000
#define NBATCH 2
#define BN_TOT (NBATCH*NPTS)       // 300000
#define CONV_BLOCKS 1172           // 256 rows/block (4 waves x 64 rows)
#define BN_PAD (CONV_BLOCKS*256)   // 300032
#define ZROW   BN_PAD              // zero feature row index
#define EPS 1e-5f
#define NBKT 8192                  // 2 batches * 16^3 coarse buckets

// ws layout (~61 MB)
#define OFF_GRID   0ull
#define SZ_GRID    ((size_t)NBATCH*GS3*4)            // 16,777,216
#define OFF_WFRAG  (OFF_GRID + SZ_GRID)
#define SZ_WFRAG   ((size_t)27*4096*2)               // 221,184
#define OFF_STATS  (OFF_WFRAG + SZ_WFRAG)            // 512
#define OFF_CNT    (OFF_STATS + 512)                 // 32,768
#define OFF_CUR    (OFF_CNT + NBKT*4)                // 32,768
#define OFF_SIDX   (OFF_CUR + NBKT*4)                // 1,200,128
#define OFF_CSORT  (OFF_SIDX + 1200128)              // BN_PAD*16
#define OFF_FB16S  (OFF_CSORT + (size_t)BN_PAD*16)   // (BN_PAD+1)*128

typedef __attribute__((ext_vector_type(8))) short bf16x8;
typedef __attribute__((ext_vector_type(4))) float f32x4;
typedef unsigned int u32;
typedef const __attribute__((address_space(1))) u32* gas_u32p;
typedef __attribute__((address_space(3))) u32* las_u32p;

__device__ __forceinline__ short f2bf(float f) {
    union { float f; unsigned u; } v; v.f = f;
    unsigned rr = v.u + 0x7fffu + ((v.u >> 16) & 1u);   // RNE
    return (short)(rr >> 16);
}

// ---------- kernel 1: grid scatter (max orig pid) + bucket histogram ----------
__global__ __launch_bounds__(256) void k_count(const int* __restrict__ coords,
                                               int* __restrict__ grid,
                                               u32* __restrict__ cnt) {
    int p = blockIdx.x*256 + threadIdx.x;
    if (p >= BN_TOT) return;
    int x = coords[p*3+0], y = coords[p*3+1], z = coords[p*3+2];
    int b = (p >= NPTS);
    atomicMax(&grid[(b<<21) | (x<<14) | (y<<7) | z], p);
    atomicAdd(&cnt[(b<<12) | ((x>>3)<<8) | ((y>>3)<<4) | (z>>3)], 1u);
}

// ---------- kernel 2: exclusive scan of 8192 bucket counts ----------
__global__ __launch_bounds__(1024) void k_scan(const u32* __restrict__ cnt,
                                               u32* __restrict__ cur) {
    __shared__ u32 ps[1024];
    int t = threadIdx.x;
    u32 l[8]; u32 s = 0;
    #pragma unroll
    for (int i = 0; i < 8; ++i) { l[i] = cnt[t*8+i]; s += l[i]; }
    ps[t] = s; __syncthreads();
    for (int off = 1; off < 1024; off <<= 1) {
        u32 v = (t >= off) ? ps[t-off] : 0u; __syncthreads();
        ps[t] += v; __syncthreads();
    }
    u32 run = (t == 0) ? 0u : ps[t-1];
    #pragma unroll
    for (int i = 0; i < 8; ++i) { cur[t*8+i] = run; run += l[i]; }
}

// ---------- kernel 3: place points in bucket order + bf16 features ----------
__global__ __launch_bounds__(256) void k_place(const float* __restrict__ feats,
                                               const int* __restrict__ coords,
                                               u32* __restrict__ cur,
                                               int* __restrict__ sortidx,
                                               int4* __restrict__ csorted,
                                               ushort* __restrict__ fb16s) {
    int p = blockIdx.x*256 + threadIdx.x;
    if (p >= BN_PAD) return;
    if (p >= BN_TOT) { csorted[p] = make_int4(-9,-9,-9,0); return; }
    int x = coords[p*3+0], y = coords[p*3+1], z = coords[p*3+2];
    int b = (p >= NPTS);
    int bkt = (b<<12) | ((x>>3)<<8) | ((y>>3)<<4) | (z>>3);
    int pos = (int)atomicAdd(&cur[bkt], 1u);
    sortidx[p] = pos;
    csorted[pos] = make_int4(x, y, z, p);
    const float4* s = (const float4*)(feats + (size_t)p*64);
    ushort* d = fb16s + (size_t)pos*64;
    #pragma unroll
    for (int i = 0; i < 8; ++i) {
        float4 a = s[2*i], c = s[2*i+1];
        ushort4 u0 = { (ushort)f2bf(a.x),(ushort)f2bf(a.y),(ushort)f2bf(a.z),(ushort)f2bf(a.w) };
        ushort4 u1 = { (ushort)f2bf(c.x),(ushort)f2bf(c.y),(ushort)f2bf(c.z),(ushort)f2bf(c.w) };
        ((ushort4*)d)[2*i] = u0; ((ushort4*)d)[2*i+1] = u1;
    }
}

// ---------- kernel 4: weight -> bf16 MFMA B-fragments ----------
__global__ __launch_bounds__(256) void k_prefrag(const float* __restrict__ w,
                                                 short* __restrict__ wfrag) {
    int t = blockIdx.x * 256 + threadIdx.x;
    if (t >= 27*4096) return;
    int i    = t & 7;
    int lane = (t >> 3) & 63;
    int tt   = (t >> 9) & 3;
    int c    = (t >> 11) & 1;
    int k    = t >> 12;
    int kk = c*32 + (lane >> 4)*8 + i;
    int co = tt*16 + (lane & 15);
    wfrag[t] = f2bf(w[(k*64 + kk)*64 + co]);
}

// ---------- kernel 5: pipelined gathered MFMA conv, inline rulebook ----------
// 4 waves/block, wave = 64 sorted rows (4 tiles) x 64 cout. Block computes its
// own 27x256 rulebook into LDS in the prologue (grid probes + sortidx).
// Steady phase k: vmcnt(8) [drains A(k)x8 + S(k)x2, keeps A(k+1)x8 flying],
// ONE s_barrier, 8 ds_read B, stage(k+1) x2, 32 MFMA (setprio), 8 A(k+2).
__global__ __launch_bounds__(256, 2) void k_conv(
    const ushort* __restrict__ fb16s,
    const int4* __restrict__ csorted,
    const int* __restrict__ grid,
    const int* __restrict__ sortidx,
    const ushort* __restrict__ wfrag,
    float* __restrict__ out,
    float* __restrict__ gstats)
{
    __shared__ __align__(16) ushort bufs[2][4096];   // 2 x 8KB B double-buffer
    __shared__ int ids_lds[27*256];                  // 27.6KB block rulebook
    __shared__ float bsum[64], bsq[64];

    const int tid  = threadIdx.x;
    const int lane = tid & 63;
    const int wv   = tid >> 6;
    const int r    = lane & 15;
    const int seg  = lane >> 4;
    const int p0b  = blockIdx.x * 256;
    const int rbase = wv*64 + r;                     // + t*16 per tile

    // ---- prologue A: inline rulebook (27 probes + sortidx per thread) ----
    {
        int4 c = csorted[p0b + tid];
        const bool pad = (p0b + tid >= BN_TOT);
        const int gb = (c.w >= NPTS) ? GS3 : 0;
        #pragma unroll
        for (int k = 0; k < 27; ++k) {
            int dx = k/9 - 1, dy = (k/3)%3 - 1, dz = k%3 - 1;   // compile-time
            int nx = c.x+dx, ny = c.y+dy, nz = c.z+dz;
            int ok = (int)(!pad & ((unsigned)nx < 128u) & ((unsigned)ny < 128u) &
                           ((unsigned)nz < 128u));
            int pid = grid[gb + ((nx&127)<<14) + ((ny&127)<<7) + (nz&127)];
            pid = ok ? pid : -1;
            int sv = sortidx[pid < 0 ? 0 : pid];
            ids_lds[k*256 + tid] = (pid >= 0) ? sv : ZROW;
        }
    }
    if (tid < 64) { bsum[tid] = 0.f; bsq[tid] = 0.f; }
    __syncthreads();                                 // rulebook ready, vmem drained

    auto stage = [&](int kk, int bsel) {             // 8KB slab, 2 instr/wave
        #pragma unroll
        for (int c = 0; c < 2; ++c) {
            int chunk = c*4 + wv;
            const u32* g = (const u32*)(wfrag + (size_t)kk*4096 + chunk*512) + lane*4;
            u32* l = (u32*)(&bufs[bsel][chunk*512]);
            __builtin_amdgcn_global_load_lds((gas_u32p)g, (las_u32p)l, 16, 0, 0);
        }
    };

#define LDA16(AC, S) { _Pragma("unroll") for (int t_ = 0; t_ < 4; ++t_) {     \
        const ushort* ap_ = fb16s + (size_t)(S)[t_]*64 + seg*8;               \
        AC[2*t_]   = *(const bf16x8*)(ap_);                                   \
        AC[2*t_+1] = *(const bf16x8*)(ap_ + 32); } }
#define LDIDS(S, kk) { _Pragma("unroll") for (int t_ = 0; t_ < 4; ++t_)       \
        S[t_] = ids_lds[(kk)*256 + rbase + t_*16]; }

    f32x4 acc[4][4];
    #pragma unroll
    for (int t = 0; t < 4; ++t)
        #pragma unroll
        for (int q = 0; q < 4; ++q) acc[t][q] = (f32x4){0,0,0,0};

    bf16x8 aE[8], aO[8];
    int sE[4], sO[4];

    // ---- prologue B: fill pipeline ----
    LDIDS(sE, 0); LDIDS(sO, 1);
    __builtin_amdgcn_sched_barrier(0);
    LDA16(aE, sE);                                   // A(0) x8
    __builtin_amdgcn_sched_barrier(0);
    stage(0, 0);                                     // S(0) x2
    __builtin_amdgcn_sched_barrier(0);
    LDA16(aO, sO);                                   // A(1) x8
    __builtin_amdgcn_sched_barrier(0);
    // invariant entering phase k: outstanding = [A(k)x8, S(k)x2, A(k+1)x8]

    auto phase = [&](int k, bf16x8 (&AC)[8]) {
        asm volatile("s_waitcnt vmcnt(8)" ::: "memory");
        __builtin_amdgcn_sched_barrier(0);
        __builtin_amdgcn_s_barrier();
        __builtin_amdgcn_sched_barrier(0);
        const ushort* bb = bufs[k & 1];
        bf16x8 b0 = *(const bf16x8*)(bb + 0*512 + lane*8);
        bf16x8 b1 = *(const bf16x8*)(bb + 1*512 + lane*8);
        bf16x8 b2 = *(const bf16x8*)(bb + 2*512 + lane*8);
        bf16x8 b3 = *(const bf16x8*)(bb + 3*512 + lane*8);
        bf16x8 b4 = *(const bf16x8*)(bb + 4*512 + lane*8);
        bf16x8 b5 = *(const bf16x8*)(bb + 5*512 + lane*8);
        bf16x8 b6 = *(const bf16x8*)(bb + 6*512 + lane*8);
        bf16x8 b7 = *(const bf16x8*)(bb + 7*512 + lane*8);
        int kp2 = (k+2 > 26) ? 26 : k+2;
        int sn[4]; LDIDS(sn, kp2);
        if (k < 26) stage(k+1, (k+1) & 1);
        __builtin_amdgcn_sched_barrier(0);
        __builtin_amdgcn_s_setprio(1);
        #pragma unroll
        for (int t = 0; t < 4; ++t) {
            acc[t][0] = __builtin_amdgcn_mfma_f32_16x16x32_bf16(AC[2*t], b0, acc[t][0], 0,0,0);
            acc[t][1] = __builtin_amdgcn_mfma_f32_16x16x32_bf16(AC[2*t], b1, acc[t][1], 0,0,0);
            acc[t][2] = __builtin_amdgcn_mfma_f32_16x16x32_bf16(AC[2*t], b2, acc[t][2], 0,0,0);
            acc[t][3] = __builtin_amdgcn_mfma_f32_16x16x32_bf16(AC[2*t], b3, acc[t][3], 0,0,0);
            acc[t][0] = __builtin_amdgcn_mfma_f32_16x16x32_bf16(AC[2*t+1], b4, acc[t][0], 0,0,0);
            acc[t][1] = __builtin_amdgcn_mfma_f32_16x16x32_bf16(AC[2*t+1], b5, acc[t][1], 0,0,0);
            acc[t][2] = __builtin_amdgcn_mfma_f32_16x16x32_bf16(AC[2*t+1], b6, acc[t][2], 0,0,0);
            acc[t][3] = __builtin_amdgcn_mfma_f32_16x16x32_bf16(AC[2*t+1], b7, acc[t][3], 0,0,0);
        }
        __builtin_amdgcn_s_setprio(0);
        __builtin_amdgcn_sched_barrier(0);
        LDA16(AC, sn);                               // A(k+2) into freed regs
        __builtin_amdgcn_sched_barrier(0);
    };

    #pragma unroll 1
    for (int t = 0; t < 13; ++t) {
        phase(2*t,   aE);
        phase(2*t+1, aO);
    }
    phase(26, aE);

    // ---- epilogue: scatter to out[orig pid]; C/D col=lane&15, row=seg*4+j ----
    #pragma unroll
    for (int t = 0; t < 4; ++t) {
        #pragma unroll
        for (int j = 0; j < 4; ++j) {
            int row = p0b + wv*64 + t*16 + seg*4 + j;
            if (row < BN_TOT) {
                int opid = csorted[row].w;
                float* ob = out + (size_t)opid*64 + r;
                ob[ 0] = acc[t][0][j];
                ob[16] = acc[t][1][j];
                ob[32] = acc[t][2][j];
                ob[48] = acc[t][3][j];
            }
        }
    }

    // ---- fused stats (pad rows contribute exact zeros) ----
    float s_[4] = {0,0,0,0}, q_[4] = {0,0,0,0};
    #pragma unroll
    for (int q = 0; q < 4; ++q)
        #pragma unroll
        for (int t = 0; t < 4; ++t)
            #pragma unroll
            for (int j = 0; j < 4; ++j) {
                float v = acc[t][q][j]; s_[q] += v; q_[q] += v*v;
            }
    #pragma unroll
    for (int q = 0; q < 4; ++q) {
        atomicAdd(&bsum[q*16 + r], s_[q]);
        atomicAdd(&bsq [q*16 + r], q_[q]);
    }
    __syncthreads();
    if (tid < 64) { atomicAdd(&gstats[tid], bsum[tid]); atomicAdd(&gstats[64+tid], bsq[tid]); }
#undef LDA16
#undef LDIDS
}

// ---------- kernel 6: normalize + affine + ReLU, in place ----------
__global__ __launch_bounds__(256) void k_norm(float* __restrict__ out,
                                              const float* __restrict__ stats,
                                              const float* __restrict__ gamma,
                                              const float* __restrict__ beta) {
    int i = blockIdx.x*256 + threadIdx.x;
    const int n4 = BN_TOT*16;
    if (i >= n4) return;
    float4 v = ((const float4*)out)[i];
    int ch = (i & 15) * 4;
    float o[4] = {v.x, v.y, v.z, v.w};
    float rp[4];
    #pragma unroll
    for (int j = 0; j < 4; ++j) {
        int c = ch + j;
        float mean = stats[c] * (1.f/BN_TOT);
        float var  = stats[64+c] * (1.f/BN_TOT) - mean*mean;
        float y = (o[j] - mean) * rsqrtf(var + EPS) * gamma[c] + beta[c];
        rp[j] = fmaxf(y, 0.f);
    }
    float4 rv; rv.x = rp[0]; rv.y = rp[1]; rv.z = rp[2]; rv.w = rp[3];
    ((float4*)out)[i] = rv;
}

extern "C" void kernel_launch(void* const* d_in, const int* in_sizes, int n_in,
                              void* d_out, int out_size, void* d_ws, size_t ws_size,
                              hipStream_t stream) {
    const float* feats  = (const float*)d_in[0];
    const int*   coords = (const int*)d_in[1];
    const float* weight = (const float*)d_in[2];
    const float* gamma  = (const float*)d_in[3];
    const float* beta   = (const float*)d_in[4];
    float* out = (float*)d_out;

    char*   ws      = (char*)d_ws;
    int*    grid    = (int*)(ws + OFF_GRID);
    short*  wfrag   = (short*)(ws + OFF_WFRAG);
    float*  stats   = (float*)(ws + OFF_STATS);
    u32*    cnt     = (u32*)(ws + OFF_CNT);
    u32*    cur     = (u32*)(ws + OFF_CUR);
    int*    sortidx = (int*)(ws + OFF_SIDX);
    int4*   csorted = (int4*)(ws + OFF_CSORT);
    ushort* fb16s   = (ushort*)(ws + OFF_FB16S);

    hipMemsetAsync(grid,  0xFF, SZ_GRID, stream);
    hipMemsetAsync(stats, 0, 512, stream);
    hipMemsetAsync(cnt,   0, NBKT*4, stream);
    hipMemsetAsync(fb16s + (size_t)BN_TOT*64, 0,
                   (size_t)(BN_PAD + 1 - BN_TOT)*128, stream);   // pads + ZROW

    k_count  <<<(BN_TOT + 255)/256, 256, 0, stream>>>(coords, grid, cnt);
    k_scan   <<<1, 1024, 0, stream>>>(cnt, cur);
    k_place  <<<(BN_PAD + 255)/256, 256, 0, stream>>>(feats, coords, cur,
                                                      sortidx, csorted, fb16s);
    k_prefrag<<<(27*4096)/256, 256, 0, stream>>>(weight, wfrag);
    k_conv   <<<CONV_BLOCKS, 256, 0, stream>>>(fb16s, csorted, grid, sortidx,
                                               (const ushort*)wfrag, out, stats);
    k_norm   <<<(BN_TOT*16)/256, 256, 0, stream>>>(out, stats, gamma, beta);
}